// Round 11
// baseline (91.069 us; speedup 1.0000x reference)
//
#include <hip/hip_runtime.h>
#include <hip/hip_bf16.h>

typedef __attribute__((ext_vector_type(4))) float f32x4;
typedef __attribute__((ext_vector_type(8))) short bf16x8;

#define MFMA16(A, B, C) __builtin_amdgcn_mfma_f32_16x16x32_bf16(A, B, C, 0, 0, 0)

// 2*log2(e): tanh(x) = 1 - 2/(1 + 2^(C2*x))
#define C2 2.8853900817779268f
// C2 / sqrt(128), folded into Wq/bq so MFMA output is already exp2-scaled
#define QS (2.8853900817779268f / 11.313708498984761f)

__device__ __forceinline__ unsigned cvtpk_bf16(float lo, float hi) {
    unsigned r;
    asm("v_cvt_pk_bf16_f32 %0, %1, %2" : "=v"(r) : "v"(lo), "v"(hi));
    return r;
}

__device__ __forceinline__ bf16x8 pack8(float4 a, float4 b) {
    union { unsigned u[4]; bf16x8 v; } u;
    u.u[0] = cvtpk_bf16(a.x, a.y);
    u.u[1] = cvtpk_bf16(a.z, a.w);
    u.u[2] = cvtpk_bf16(b.x, b.y);
    u.u[3] = cvtpk_bf16(b.z, b.w);
    return u.v;
}

// async global->LDS, 16B per lane; LDS dest = wave-uniform base + lane*16
__device__ __forceinline__ void gload_lds16(const void* g, void* l) {
    __builtin_amdgcn_global_load_lds(
        (const __attribute__((address_space(1))) unsigned int*)g,
        (__attribute__((address_space(3))) unsigned int*)l, 16, 0, 0);
}

// ---------------------------------------------------------------------------
// Kernel 1: transpose + convert weights to bf16, fold scales, stash biases.
// ---------------------------------------------------------------------------
__global__ void prep_weights(const float* __restrict__ Wq, const float* __restrict__ bq,
                             const float* __restrict__ Wk, const float* __restrict__ bk,
                             const float* __restrict__ Wv, const float* __restrict__ bv,
                             __hip_bfloat16* __restrict__ Wqt, __hip_bfloat16* __restrict__ Wkt,
                             __hip_bfloat16* __restrict__ Wvt, float* __restrict__ bias) {
    int i = blockIdx.x * 256 + threadIdx.x;  // 64 blocks * 256 = 16384 exactly
    int k = i >> 7, o = i & 127;
    Wqt[o * 128 + k] = __float2bfloat16(Wq[i] * QS);
    Wkt[o * 128 + k] = __float2bfloat16(Wk[i]);
    Wvt[o * 128 + k] = __float2bfloat16(Wv[i] * 0.25f);  // head-mean folded into V
    if (i < 128) {
        bias[i]       = bq[i] * QS;
        bias[128 + i] = bk[i];
        bias[256 + i] = bv[i] * 0.25f;
    }
}

// ---------------------------------------------------------------------------
// Kernel 2: Q/K/V projections via 16x16x32 bf16 MFMA.
//   Qo, Ko: row-major [B*N][128] bf16 (Q pre-scaled by C2/sqrt(128))
//   Vt:     transposed [B][128][N] bf16 (pre-scaled by 0.25)
// ---------------------------------------------------------------------------
__global__ __launch_bounds__(256) void proj_qkv(
        const float* __restrict__ x, const float* __restrict__ cond,
        const __hip_bfloat16* __restrict__ Wqt, const __hip_bfloat16* __restrict__ Wkt,
        const __hip_bfloat16* __restrict__ Wvt, const float* __restrict__ bias,
        __hip_bfloat16* __restrict__ Qo, __hip_bfloat16* __restrict__ Ko,
        __hip_bfloat16* __restrict__ Vt) {
    const int lane = threadIdx.x & 63, wv = threadIdx.x >> 6;
    const int l15 = lane & 15, g = lane >> 4;
    const int row0 = blockIdx.x * 64 + wv * 16;   // 256 blocks x 64 rows

    f32x4 qa[8], ka[8], va[8];
#pragma unroll
    for (int ot = 0; ot < 8; ++ot) {
        float b0 = bias[16 * ot + l15];
        float b1 = bias[128 + 16 * ot + l15];
        float b2 = bias[256 + 16 * ot + l15];
        qa[ot] = (f32x4){b0, b0, b0, b0};
        ka[ot] = (f32x4){b1, b1, b1, b1};
        va[ot] = (f32x4){b2, b2, b2, b2};
    }

    const float* xp = x    + (size_t)(row0 + l15) * 128 + 8 * g;
    const float* cp = cond + (size_t)(row0 + l15) * 128 + 8 * g;
#pragma unroll
    for (int kk = 0; kk < 4; ++kk) {
        float4 x0 = *(const float4*)(xp + 32 * kk);
        float4 x1 = *(const float4*)(xp + 32 * kk + 4);
        float4 c0 = *(const float4*)(cp + 32 * kk);
        float4 c1 = *(const float4*)(cp + 32 * kk + 4);
        bf16x8 xa = pack8(x0, x1);
        bf16x8 ca = pack8(c0, c1);
#pragma unroll
        for (int ot = 0; ot < 8; ++ot) {
            const int wo = (16 * ot + l15) * 128 + 32 * kk + 8 * g;
            qa[ot] = MFMA16(xa, *(const bf16x8*)(Wqt + wo), qa[ot]);
            ka[ot] = MFMA16(ca, *(const bf16x8*)(Wkt + wo), ka[ot]);
            va[ot] = MFMA16(ca, *(const bf16x8*)(Wvt + wo), va[ot]);
        }
    }

    // Q, K row-major stores (C/D layout: row = 4g+r, col = 16ot+l15)
#pragma unroll
    for (int ot = 0; ot < 8; ++ot)
#pragma unroll
        for (int r = 0; r < 4; ++r) {
            size_t idx = (size_t)(row0 + 4 * g + r) * 128 + 16 * ot + l15;
            Qo[idx] = __float2bfloat16(qa[ot][r]);
            Ko[idx] = __float2bfloat16(ka[ot][r]);
        }
    // V transposed store: lane holds 4 consecutive n for fixed d -> dwordx2
    const int bb = row0 >> 11, nn = (row0 & 2047) + 4 * g;
#pragma unroll
    for (int ot = 0; ot < 8; ++ot) {
        uint2 pr;
        pr.x = cvtpk_bf16(va[ot][0], va[ot][1]);
        pr.y = cvtpk_bf16(va[ot][2], va[ot][3]);
        *(uint2*)((unsigned short*)Vt + ((size_t)bb * 128 + 16 * ot + l15) * 2048 + nn) = pr;
    }
}

// ---------------------------------------------------------------------------
// Kernel 3: fused tanh-attention, skewed pipeline + DEPTH-2 counted-vmcnt
// staging (R11). R6-R10 post-mortem: every variant ended regions with
// vmcnt(0), draining the stage issued in the SAME region -> effective
// prefetch depth 0, fixed ~2-3K cyc/region. Here region c issues exactly
// 3 VMEM ops: K-stage(c+2), V-stage(c+1), mask(c+2); the region ends with
// vmcnt(3), which keeps those 3 in flight across the barrier and provably
// drains everything older (K(c+1): needed next region; V(c): needed next
// region by PV; both got a full region of flight). Buffers:
//   K[3]: stage (c+2)%3, QK reads c%3        A[2]: QK writes c&1,
//   V[3]: stage (c+1)%3, PV reads (c-1)%3          PV reads (c-1)&1
// Edges: c==30 -> vmcnt(2), c==31 -> vmcnt(0). LDS 59.4 KB, 2 blocks/CU.
// ---------------------------------------------------------------------------
__global__ __launch_bounds__(512) void attn_main(
        const __hip_bfloat16* __restrict__ Q, const __hip_bfloat16* __restrict__ K,
        const __hip_bfloat16* __restrict__ Vt, const float* __restrict__ mask,
        float* __restrict__ out) {
    __shared__ __align__(16) char Kl[3][8192];   // [32 m][256B] per buf
    __shared__ __align__(16) char Vl[3][8192];   // [128 d][64B] per buf
    __shared__ __align__(16) char Al[2][5120];   // [64 q][80B (40 bf16)]

    const int lane = threadIdx.x & 63, w = threadIdx.x >> 6;
    const int l15 = lane & 15, g = lane >> 4;
    const int qw = w & 3, mw = w >> 2, dw = mw;
    const int qt = blockIdx.x & 31;
    const int mh = (blockIdx.x >> 5) & 1;
    const int b  = blockIdx.x >> 6;
    const int n0 = qt * 64;
    const int mh0 = mh * 1024;

    const __hip_bfloat16* Qb = Q + ((size_t)b * 2048 + n0 + qw * 16) * 128;
    const char* Kg = (const char*)(K + (size_t)b * 2048 * 128);
    const char* Vg = (const char*)(Vt + (size_t)b * 128 * 2048);
    // lane's mask base: q-row (n0+qw*16+l15), m = mh0 + mw*16 + 4g
    const float* mrow = mask + ((size_t)b * 2048 + n0 + qw * 16 + l15) * 2048
                        + mh0 + mw * 16 + 4 * g;

    bf16x8 qf[4];
#pragma unroll
    for (int h = 0; h < 4; ++h)
        qf[h] = *(const bf16x8*)(Qb + l15 * 128 + 32 * h + 8 * g);

    f32x4 oacc[4];
#pragma unroll
    for (int dtl = 0; dtl < 4; ++dtl) oacc[dtl] = (f32x4){0.f, 0.f, 0.f, 0.f};
    const f32x4 zero = (f32x4){0.f, 0.f, 0.f, 0.f};

    // 1 KB per wave per buffer; linear LDS dest, XOR-swizzled global source
    auto STAGE_K = [&](int m0g, int kb) {
        const int o = w * 1024 + lane * 16;
        const int kr = o >> 8, kc = o & 255;          // 32 rows x 256B
        gload_lds16(Kg + (size_t)(m0g + kr) * 256 + (kc ^ ((kr & 15) << 4)),
                    &Kl[kb][w * 1024]);
    };
    auto STAGE_V = [&](int m0g, int vb) {
        const int o = w * 1024 + lane * 16;
        const int vr = o >> 6, vc = o & 63;           // 128 rows x 64B
        gload_lds16(Vg + (size_t)vr * 4096 + (size_t)m0g * 2 + (vc ^ ((vr & 3) << 4)),
                    &Vl[vb][w * 1024]);
    };

    // prologue: group0 = {K(0), V(0), mask(0)}; fence; group1 = {K(1), mask(1)}
    // vmcnt(2) leaves group1 in flight, drains group0.
    STAGE_K(mh0, 0);
    STAGE_V(mh0, 0);
    f32x4 mkc = *(const f32x4*)(mrow);
    asm volatile("" ::: "memory");
    STAGE_K(mh0 + 32, 1);
    f32x4 mkn = *(const f32x4*)(mrow + 32);
    asm volatile("s_waitcnt vmcnt(2)" ::: "memory");
    __builtin_amdgcn_s_barrier();

    int kb_st = 2, kb_rd = 0;   // K: stage (c+2)%3, read c%3
    int vb_st = 1, vb_pv = 2;   // V: stage (c+1)%3, PV reads (c-1)%3

#pragma unroll 2
    for (int c = 0; c < 32; ++c) {
        const int abi = c & 1;
        // region VMEM issue (<=3 ops): K(c+2), V(c+1), mask(c+2)
        f32x4 mk2;
        if (c < 30) {
            STAGE_K(mh0 + (c + 2) * 32, kb_st);
            mk2 = *(const f32x4*)(mrow + (c + 2) * 32);
        }
        if (c < 31) STAGE_V(mh0 + (c + 1) * 32, vb_st);

        // ---- QK + tanh (chunk c): wave's 16q x 16m -> A[abi] ----
        {
            const int mr = mw * 16 + l15;            // K row within chunk
            const char* kb = &Kl[kb_rd][mr * 256];
            const int sw = l15 << 4;
            f32x4 s0 = MFMA16(*(const bf16x8*)(kb + ((g * 16) ^ sw)),       qf[0], zero);
            f32x4 s1 = MFMA16(*(const bf16x8*)(kb + ((64 + g * 16) ^ sw)),  qf[1], zero);
            f32x4 s2 = MFMA16(*(const bf16x8*)(kb + ((128 + g * 16) ^ sw)), qf[2], zero);
            f32x4 s3 = MFMA16(*(const bf16x8*)(kb + ((192 + g * 16) ^ sw)), qf[3], zero);
            float acd[4];
#pragma unroll
            for (int r = 0; r < 4; ++r) {
                float m2 = mkc[r] * C2;
                float e0 = __builtin_amdgcn_exp2f(m2 + s0[r]);
                float e1 = __builtin_amdgcn_exp2f(m2 + s1[r]);
                float e2 = __builtin_amdgcn_exp2f(m2 + s2[r]);
                float e3 = __builtin_amdgcn_exp2f(m2 + s3[r]);
                float rs = __builtin_amdgcn_rcpf(1.f + e0) + __builtin_amdgcn_rcpf(1.f + e1)
                         + __builtin_amdgcn_rcpf(1.f + e2) + __builtin_amdgcn_rcpf(1.f + e3);
                acd[r] = 4.f - 2.f * rs;   // sum_h tanh(...)
            }
            // transpose write: row q=l15, cols m_local = mw*16 + 4g + 0..3
            uint2 pk;
            pk.x = cvtpk_bf16(acd[0], acd[1]);
            pk.y = cvtpk_bf16(acd[2], acd[3]);
            *(uint2*)(&Al[abi][(qw * 16 + l15) * 80 + (mw * 16 + 4 * g) * 2]) = pk;
        }

        // ---- PV (chunk c-1): wave's 16q x 64d from A[abi^1] + V[vb_pv] ----
        if (c > 0) {
            bf16x8 af = *(const bf16x8*)(&Al[abi ^ 1][(qw * 16 + l15) * 80 + g * 16]);
#pragma unroll
            for (int dtl = 0; dtl < 4; ++dtl) {
                const int dr = dw * 64 + dtl * 16 + l15;
                bf16x8 vf = *(const bf16x8*)(
                    &Vl[vb_pv][dr * 64 + ((g * 16) ^ ((dr & 3) << 4))]);
                oacc[dtl] = MFMA16(af, vf, oacc[dtl]);
            }
        }

        // counted drain: keep THIS region's <=3 VMEM ops in flight; force
        // everything older (K(c+1), V(c) -- both needed next region) done.
        if (c < 30)       asm volatile("s_waitcnt vmcnt(3)" ::: "memory");
        else if (c == 30) asm volatile("s_waitcnt vmcnt(2)" ::: "memory");
        else              asm volatile("s_waitcnt vmcnt(0)" ::: "memory");
        asm volatile("s_waitcnt lgkmcnt(0)" ::: "memory");
        __builtin_amdgcn_s_barrier();

        mkc = mkn; mkn = mk2;
        kb_st = (kb_st == 2) ? 0 : kb_st + 1;
        kb_rd = (kb_rd == 2) ? 0 : kb_rd + 1;
        vb_st = (vb_st == 2) ? 0 : vb_st + 1;
        vb_pv = (vb_pv == 2) ? 0 : vb_pv + 1;
    }

    // drain: PV(31) from A[1] + V[31%3 = 1] (vb_pv rotated to 1... verify:
    // vb_pv starts 2, 32 increments -> (2+32)%3 = 1 = 31%3  ✓)
    {
        bf16x8 af = *(const bf16x8*)(&Al[1][(qw * 16 + l15) * 80 + g * 16]);
#pragma unroll
        for (int dtl = 0; dtl < 4; ++dtl) {
            const int dr = dw * 64 + dtl * 16 + l15;
            bf16x8 vf = *(const bf16x8*)(
                &Vl[vb_pv][dr * 64 + ((g * 16) ^ ((dr & 3) << 4))]);
            oacc[dtl] = MFMA16(af, vf, oacc[dtl]);
        }
    }

    // epilogue: per-wave-disjoint 16q x 64d tile; 2 m-half blocks contend
    float* ob = out + ((size_t)b * 2048 + n0 + qw * 16) * 128 + dw * 64;
#pragma unroll
    for (int dtl = 0; dtl < 4; ++dtl)
#pragma unroll
        for (int r = 0; r < 4; ++r)
            unsafeAtomicAdd(&ob[(size_t)(4 * g + r) * 128 + dtl * 16 + l15], oacc[dtl][r]);
}

// ---------------------------------------------------------------------------
extern "C" void kernel_launch(void* const* d_in, const int* in_sizes, int n_in,
                              void* d_out, int out_size, void* d_ws, size_t ws_size,
                              hipStream_t stream) {
    const float* x    = (const float*)d_in[0];
    const float* cond = (const float*)d_in[1];
    // d_in[2] = flags (unused by reference)
    const float* mask = (const float*)d_in[3];
    const float* Wq = (const float*)d_in[4];
    const float* bq = (const float*)d_in[5];
    const float* Wk = (const float*)d_in[6];
    const float* bk = (const float*)d_in[7];
    const float* Wv = (const float*)d_in[8];
    const float* bv = (const float*)d_in[9];
    float* out = (float*)d_out;

    char* ws = (char*)d_ws;
    __hip_bfloat16* Qo  = (__hip_bfloat16*)(ws);                       // 4 MB
    __hip_bfloat16* Ko  = (__hip_bfloat16*)(ws + (4  << 20));          // 4 MB
    __hip_bfloat16* Vt  = (__hip_bfloat16*)(ws + (8  << 20));          // 4 MB
    __hip_bfloat16* Wqt = (__hip_bfloat16*)(ws + (12 << 20));          // 32 KB
    __hip_bfloat16* Wkt = (__hip_bfloat16*)(ws + (12 << 20) + 32768);
    __hip_bfloat16* Wvt = (__hip_bfloat16*)(ws + (12 << 20) + 65536);
    float*          bias = (float*)(ws + (12 << 20) + 98304);          // 1.5 KB

    // out accumulates atomic partials from 2 m-half blocks -> zero it first
    hipMemsetAsync(d_out, 0, (size_t)out_size * sizeof(float), stream);

    prep_weights<<<64, 256, 0, stream>>>(Wq, bq, Wk, bk, Wv, bv, Wqt, Wkt, Wvt, bias);
    proj_qkv<<<256, 256, 0, stream>>>(x, cond, Wqt, Wkt, Wvt, bias, Qo, Ko, Vt);
    attn_main<<<512, 512, 0, stream>>>(Qo, Ko, Vt, mask, out);
}

// Round 12
// 87.065 us; speedup vs baseline: 1.0460x; 1.0460x over previous
//
#include <hip/hip_runtime.h>
#include <hip/hip_bf16.h>

typedef __attribute__((ext_vector_type(4))) float f32x4;
typedef __attribute__((ext_vector_type(8))) short bf16x8;

#define MFMA16(A, B, C) __builtin_amdgcn_mfma_f32_16x16x32_bf16(A, B, C, 0, 0, 0)

// 2*log2(e): tanh(x) = 1 - 2/(1 + 2^(C2*x))
#define C2 2.8853900817779268f
// C2 / sqrt(128), folded into Wq/bq so MFMA output is already exp2-scaled
#define QS (2.8853900817779268f / 11.313708498984761f)

__device__ __forceinline__ unsigned cvtpk_bf16(float lo, float hi) {
    unsigned r;
    asm("v_cvt_pk_bf16_f32 %0, %1, %2" : "=v"(r) : "v"(lo), "v"(hi));
    return r;
}

__device__ __forceinline__ bf16x8 pack8(float4 a, float4 b) {
    union { unsigned u[4]; bf16x8 v; } u;
    u.u[0] = cvtpk_bf16(a.x, a.y);
    u.u[1] = cvtpk_bf16(a.z, a.w);
    u.u[2] = cvtpk_bf16(b.x, b.y);
    u.u[3] = cvtpk_bf16(b.z, b.w);
    return u.v;
}

// async global->LDS, 16B per lane; LDS dest = wave-uniform base + lane*16
__device__ __forceinline__ void gload_lds16(const void* g, void* l) {
    __builtin_amdgcn_global_load_lds(
        (const __attribute__((address_space(1))) unsigned int*)g,
        (__attribute__((address_space(3))) unsigned int*)l, 16, 0, 0);
}

// ---------------------------------------------------------------------------
// Kernel 1: transpose + convert weights to bf16, fold scales, stash biases.
// ---------------------------------------------------------------------------
__global__ void prep_weights(const float* __restrict__ Wq, const float* __restrict__ bq,
                             const float* __restrict__ Wk, const float* __restrict__ bk,
                             const float* __restrict__ Wv, const float* __restrict__ bv,
                             __hip_bfloat16* __restrict__ Wqt, __hip_bfloat16* __restrict__ Wkt,
                             __hip_bfloat16* __restrict__ Wvt, float* __restrict__ bias) {
    int i = blockIdx.x * 256 + threadIdx.x;  // 64 blocks * 256 = 16384 exactly
    int k = i >> 7, o = i & 127;
    Wqt[o * 128 + k] = __float2bfloat16(Wq[i] * QS);
    Wkt[o * 128 + k] = __float2bfloat16(Wk[i]);
    Wvt[o * 128 + k] = __float2bfloat16(Wv[i] * 0.25f);  // head-mean folded into V
    if (i < 128) {
        bias[i]       = bq[i] * QS;
        bias[128 + i] = bk[i];
        bias[256 + i] = bv[i] * 0.25f;
    }
}

// ---------------------------------------------------------------------------
// Kernel 2: Q/K/V projections via 16x16x32 bf16 MFMA.
//   Qo, Ko: row-major [B*N][128] bf16 (Q pre-scaled by C2/sqrt(128))
//   Vt:     transposed [B][128][N] bf16 (pre-scaled by 0.25)
// ---------------------------------------------------------------------------
__global__ __launch_bounds__(256) void proj_qkv(
        const float* __restrict__ x, const float* __restrict__ cond,
        const __hip_bfloat16* __restrict__ Wqt, const __hip_bfloat16* __restrict__ Wkt,
        const __hip_bfloat16* __restrict__ Wvt, const float* __restrict__ bias,
        __hip_bfloat16* __restrict__ Qo, __hip_bfloat16* __restrict__ Ko,
        __hip_bfloat16* __restrict__ Vt) {
    const int lane = threadIdx.x & 63, wv = threadIdx.x >> 6;
    const int l15 = lane & 15, g = lane >> 4;
    const int row0 = blockIdx.x * 64 + wv * 16;   // 256 blocks x 64 rows

    f32x4 qa[8], ka[8], va[8];
#pragma unroll
    for (int ot = 0; ot < 8; ++ot) {
        float b0 = bias[16 * ot + l15];
        float b1 = bias[128 + 16 * ot + l15];
        float b2 = bias[256 + 16 * ot + l15];
        qa[ot] = (f32x4){b0, b0, b0, b0};
        ka[ot] = (f32x4){b1, b1, b1, b1};
        va[ot] = (f32x4){b2, b2, b2, b2};
    }

    const float* xp = x    + (size_t)(row0 + l15) * 128 + 8 * g;
    const float* cp = cond + (size_t)(row0 + l15) * 128 + 8 * g;
#pragma unroll
    for (int kk = 0; kk < 4; ++kk) {
        float4 x0 = *(const float4*)(xp + 32 * kk);
        float4 x1 = *(const float4*)(xp + 32 * kk + 4);
        float4 c0 = *(const float4*)(cp + 32 * kk);
        float4 c1 = *(const float4*)(cp + 32 * kk + 4);
        bf16x8 xa = pack8(x0, x1);
        bf16x8 ca = pack8(c0, c1);
#pragma unroll
        for (int ot = 0; ot < 8; ++ot) {
            const int wo = (16 * ot + l15) * 128 + 32 * kk + 8 * g;
            qa[ot] = MFMA16(xa, *(const bf16x8*)(Wqt + wo), qa[ot]);
            ka[ot] = MFMA16(ca, *(const bf16x8*)(Wkt + wo), ka[ot]);
            va[ot] = MFMA16(ca, *(const bf16x8*)(Wvt + wo), va[ot]);
        }
    }

    // Q, K row-major stores (C/D layout: row = 4g+r, col = 16ot+l15)
#pragma unroll
    for (int ot = 0; ot < 8; ++ot)
#pragma unroll
        for (int r = 0; r < 4; ++r) {
            size_t idx = (size_t)(row0 + 4 * g + r) * 128 + 16 * ot + l15;
            Qo[idx] = __float2bfloat16(qa[ot][r]);
            Ko[idx] = __float2bfloat16(ka[ot][r]);
        }
    // V transposed store: lane holds 4 consecutive n for fixed d -> dwordx2
    const int bb = row0 >> 11, nn = (row0 & 2047) + 4 * g;
#pragma unroll
    for (int ot = 0; ot < 8; ++ot) {
        uint2 pr;
        pr.x = cvtpk_bf16(va[ot][0], va[ot][1]);
        pr.y = cvtpk_bf16(va[ot][2], va[ot][3]);
        *(uint2*)((unsigned short*)Vt + ((size_t)bb * 128 + 16 * ot + l15) * 2048 + nn) = pr;
    }
}

// ---------------------------------------------------------------------------
// Kernel 3: fused tanh-attention, LDS-staged (R12 = R6 + XCD-pinned batch).
// R6-R11 post-mortem: all sync restructures flat at 77-93 us; per-region
// stall ~6K cyc is insensitive to barriers/prefetch-depth/occupancy ->
// the stall is the STAGE SOURCE latency: with round-robin blockIdx->XCD,
// every XCD hosts blocks of all 8 batches -> per-XCD K/V/Q working set
// 12 MB >> 4 MB L2 -> every stage read is an L2 miss. Remap b = blockIdx&7
// so batch == XCD (64 blocks per XCD = exactly its 2-blocks/CU capacity);
// per-XCD working set drops to 1.5 MB -> stage reads become L2 hits.
// Structure otherwise IDENTICAL to R6 (77 us): 8 waves, 64q x 1024m per
// block, 64-m chunks, K+V double-buffered, lgkm mid-barrier, vmcnt(0)
// end-barrier.
// ---------------------------------------------------------------------------
__global__ __launch_bounds__(512) void attn_main(
        const __hip_bfloat16* __restrict__ Q, const __hip_bfloat16* __restrict__ K,
        const __hip_bfloat16* __restrict__ Vt, const float* __restrict__ mask,
        float* __restrict__ out) {
    __shared__ __align__(16) char Kl[2][16384];   // [64 m][256B] per buf
    __shared__ __align__(16) char Vl[2][16384];   // [128 d][128B] per buf
    __shared__ __align__(16) char Al[64 * 144];   // [64 q][72 bf16]

    const int lane = threadIdx.x & 63, w = threadIdx.x >> 6;
    const int l15 = lane & 15, g = lane >> 4;
    const int qw = w & 3, mw = w >> 2, dw = mw;
    // XCD-pinned decomposition: batch = blockIdx & 7 (== XCD under round-robin)
    const int b  = blockIdx.x & 7;
    const int r2 = blockIdx.x >> 3;
    const int qt = r2 & 31;
    const int mh = r2 >> 5;
    const int n0 = qt * 64;
    const int mh0 = mh * 1024;

    const __hip_bfloat16* Qb = Q + ((size_t)b * 2048 + n0 + qw * 16) * 128;
    const char* Kg = (const char*)(K + (size_t)b * 2048 * 128);
    const char* Vg = (const char*)(Vt + (size_t)b * 128 * 2048);
    const float* mrow = mask + ((size_t)b * 2048 + n0 + qw * 16 + l15) * 2048
                        + mh0 + mw * 32 + 4 * g;

    bf16x8 qf[4];
#pragma unroll
    for (int h = 0; h < 4; ++h)
        qf[h] = *(const bf16x8*)(Qb + l15 * 128 + 32 * h + 8 * g);

    f32x4 oacc[4];
#pragma unroll
    for (int dtl = 0; dtl < 4; ++dtl) oacc[dtl] = (f32x4){0.f, 0.f, 0.f, 0.f};
    const f32x4 zero = (f32x4){0.f, 0.f, 0.f, 0.f};

    // ---- staging: 2 K-instr + 2 V-instr per wave (1 KB each, linear LDS) --
    auto STAGE = [&](int m0g, int bi) {
#pragma unroll
        for (int i = 0; i < 2; ++i) {
            const int t = w * 2 + i;
            const int o = t * 1024 + lane * 16;
            const int kr = o >> 8, kc = o & 255;
            gload_lds16(Kg + (size_t)(m0g + kr) * 256 + (kc ^ ((kr & 7) << 4)),
                        &Kl[bi][t * 1024]);
            const int vr = o >> 7, vc = o & 127;
            gload_lds16(Vg + (size_t)vr * 4096 + (size_t)m0g * 2 + (vc ^ ((vr & 7) << 4)),
                        &Vl[bi][t * 1024]);
        }
    };

    // prologue: stage chunk 0, prefetch mask chunk 0
    STAGE(mh0, 0);
    f32x4 mkc0 = *(const f32x4*)(mrow);
    f32x4 mkc1 = *(const f32x4*)(mrow + 16);
    asm volatile("s_waitcnt vmcnt(0)" ::: "memory");
    __builtin_amdgcn_s_barrier();

#pragma unroll 2
    for (int c = 0; c < 16; ++c) {
        const int bi = c & 1;
        const int m0g = mh0 + c * 64;
        // issue next chunk's stage + mask prefetch (stay in flight all chunk)
        if (c < 15) STAGE(m0g + 64, bi ^ 1);
        f32x4 mkn0, mkn1;
        if (c < 15) {
            mkn0 = *(const f32x4*)(mrow + (c + 1) * 64);
            mkn1 = *(const f32x4*)(mrow + (c + 1) * 64 + 16);
        }

        // ---- QK + tanh + A-write (wave's 16q x 32m) ----
#pragma unroll
        for (int st = 0; st < 2; ++st) {
            const int mr = mw * 32 + st * 16 + l15;
            const char* kb = &Kl[bi][mr * 256];
            const int sw = (mr & 7) << 4;
            f32x4 s0 = MFMA16(*(const bf16x8*)(kb + ((g * 16) ^ sw)),       qf[0], zero);
            f32x4 s1 = MFMA16(*(const bf16x8*)(kb + ((64 + g * 16) ^ sw)),  qf[1], zero);
            f32x4 s2 = MFMA16(*(const bf16x8*)(kb + ((128 + g * 16) ^ sw)), qf[2], zero);
            f32x4 s3 = MFMA16(*(const bf16x8*)(kb + ((192 + g * 16) ^ sw)), qf[3], zero);
            const f32x4 mk = st ? mkc1 : mkc0;
            float acd[4];
#pragma unroll
            for (int r = 0; r < 4; ++r) {
                float m2 = mk[r] * C2;
                float e0 = __builtin_amdgcn_exp2f(m2 + s0[r]);
                float e1 = __builtin_amdgcn_exp2f(m2 + s1[r]);
                float e2 = __builtin_amdgcn_exp2f(m2 + s2[r]);
                float e3 = __builtin_amdgcn_exp2f(m2 + s3[r]);
                float rs = __builtin_amdgcn_rcpf(1.f + e0) + __builtin_amdgcn_rcpf(1.f + e1)
                         + __builtin_amdgcn_rcpf(1.f + e2) + __builtin_amdgcn_rcpf(1.f + e3);
                acd[r] = 4.f - 2.f * rs;   // sum_h tanh(...)
            }
            uint2 pk;
            pk.x = cvtpk_bf16(acd[0], acd[1]);
            pk.y = cvtpk_bf16(acd[2], acd[3]);
            *(uint2*)(Al + (qw * 16 + l15) * 144 + (mw * 32 + st * 16 + 4 * g) * 2) = pk;
        }

        // A visible block-wide; do NOT drain vmcnt (stage stays in flight)
        asm volatile("s_waitcnt lgkmcnt(0)" ::: "memory");
        __builtin_amdgcn_s_barrier();

        // ---- PV: wave's 16q x 64d over this chunk's 64 m ----
#pragma unroll
        for (int ks = 0; ks < 2; ++ks) {
            bf16x8 af = *(const bf16x8*)(Al + (qw * 16 + l15) * 144 + (ks * 32 + 8 * g) * 2);
#pragma unroll
            for (int dtl = 0; dtl < 4; ++dtl) {
                const int dr = dw * 64 + dtl * 16 + l15;
                bf16x8 vf = *(const bf16x8*)(
                    &Vl[bi][dr * 128 + ((ks * 64 + g * 16) ^ ((dr & 7) << 4))]);
                oacc[dtl] = MFMA16(af, vf, oacc[dtl]);
            }
        }

        // own stage complete, then joint barrier: everyone staged + reads done
        asm volatile("s_waitcnt vmcnt(0)" ::: "memory");
        __builtin_amdgcn_s_barrier();

        mkc0 = mkn0;
        mkc1 = mkn1;
    }

    // epilogue: per-wave-disjoint 16q x 64d tile; 2 m-half blocks contend
    float* ob = out + ((size_t)b * 2048 + n0 + qw * 16) * 128 + dw * 64;
#pragma unroll
    for (int dtl = 0; dtl < 4; ++dtl)
#pragma unroll
        for (int r = 0; r < 4; ++r)
            unsafeAtomicAdd(&ob[(size_t)(4 * g + r) * 128 + dtl * 16 + l15], oacc[dtl][r]);
}

// ---------------------------------------------------------------------------
extern "C" void kernel_launch(void* const* d_in, const int* in_sizes, int n_in,
                              void* d_out, int out_size, void* d_ws, size_t ws_size,
                              hipStream_t stream) {
    const float* x    = (const float*)d_in[0];
    const float* cond = (const float*)d_in[1];
    // d_in[2] = flags (unused by reference)
    const float* mask = (const float*)d_in[3];
    const float* Wq = (const float*)d_in[4];
    const float* bq = (const float*)d_in[5];
    const float* Wk = (const float*)d_in[6];
    const float* bk = (const float*)d_in[7];
    const float* Wv = (const float*)d_in[8];
    const float* bv = (const float*)d_in[9];
    float* out = (float*)d_out;

    char* ws = (char*)d_ws;
    __hip_bfloat16* Qo  = (__hip_bfloat16*)(ws);                       // 4 MB
    __hip_bfloat16* Ko  = (__hip_bfloat16*)(ws + (4  << 20));          // 4 MB
    __hip_bfloat16* Vt  = (__hip_bfloat16*)(ws + (8  << 20));          // 4 MB
    __hip_bfloat16* Wqt = (__hip_bfloat16*)(ws + (12 << 20));          // 32 KB
    __hip_bfloat16* Wkt = (__hip_bfloat16*)(ws + (12 << 20) + 32768);
    __hip_bfloat16* Wvt = (__hip_bfloat16*)(ws + (12 << 20) + 65536);
    float*          bias = (float*)(ws + (12 << 20) + 98304);          // 1.5 KB

    // out accumulates atomic partials from 2 m-half blocks -> zero it first
    hipMemsetAsync(d_out, 0, (size_t)out_size * sizeof(float), stream);

    prep_weights<<<64, 256, 0, stream>>>(Wq, bq, Wk, bk, Wv, bv, Wqt, Wkt, Wvt, bias);
    proj_qkv<<<256, 256, 0, stream>>>(x, cond, Wqt, Wkt, Wvt, bias, Qo, Ko, Vt);
    attn_main<<<512, 512, 0, stream>>>(Qo, Ko, Vt, mask, out);
}